// Round 1
// baseline (597.058 us; speedup 1.0000x reference)
//
#include <hip/hip_runtime.h>
#include <hip/hip_bf16.h>

// GAT: N=50000 nodes, E=850000 edges, HID=128, HEADS=8, DH=16, LAYERS=2.
// Pipeline: CSR build -> encoder GEMM -> 2x (repack W, transform+alpha, aggregate).
// All fp32 for round-0 correctness.

#define NPB 8  // nodes per block in GEMM kernels

// ---------------- CSR build ----------------

__global__ void hist_kernel(const int* __restrict__ row, int* __restrict__ deg, int E) {
    int e = blockIdx.x * 256 + threadIdx.x;
    if (e < E) atomicAdd(&deg[row[e]], 1);
}

__global__ void scan_kernel(const int* __restrict__ deg, int* __restrict__ rowptr,
                            int* __restrict__ cursor, int n) {
    const int ITEMS = 8, T = 1024;
    __shared__ int buf[T];
    int tid = threadIdx.x;
    int base = 0;
    for (int chunk0 = 0; chunk0 < n; chunk0 += T * ITEMS) {
        int v[ITEMS];
        int s = 0;
#pragma unroll
        for (int i = 0; i < ITEMS; i++) {
            int idx = chunk0 + tid * ITEMS + i;
            v[i] = (idx < n) ? deg[idx] : 0;
            s += v[i];
        }
        buf[tid] = s;
        __syncthreads();
        for (int off = 1; off < T; off <<= 1) {
            int t2 = (tid >= off) ? buf[tid - off] : 0;
            __syncthreads();
            buf[tid] += t2;
            __syncthreads();
        }
        int excl = buf[tid] - s + base;  // exclusive prefix of this thread's first item
        int total = buf[T - 1];
#pragma unroll
        for (int i = 0; i < ITEMS; i++) {
            int idx = chunk0 + tid * ITEMS + i;
            if (idx < n) { rowptr[idx] = excl; cursor[idx] = excl; }
            excl += v[i];
        }
        __syncthreads();
        base += total;
    }
    if (tid == 0) rowptr[n] = base;
}

__global__ void scatter_kernel(const int* __restrict__ row, const int* __restrict__ colv,
                               const float* __restrict__ ev, int* __restrict__ cursor,
                               int* __restrict__ csr_col, float* __restrict__ csr_val, int E) {
    int e = blockIdx.x * 256 + threadIdx.x;
    if (e < E) {
        int r = row[e];
        int slot = atomicAdd(&cursor[r], 1);
        csr_col[slot] = colv[e];
        csr_val[slot] = ev[e];
    }
}

// ---------------- encoder GEMM: out = x @ W + b ----------------

__global__ void encoder_kernel(const float* __restrict__ x, const float* __restrict__ W,
                               const float* __restrict__ b, float* __restrict__ out, int n) {
    __shared__ float xs[NPB][128];
    int t = threadIdx.x;  // 128 threads; thread t = output column t
    int n0 = blockIdx.x * NPB;
#pragma unroll
    for (int i = 0; i < NPB; i++) {
        int nn = n0 + i;
        xs[i][t] = (nn < n) ? x[(size_t)nn * 128 + t] : 0.f;
    }
    __syncthreads();
    float acc[NPB];
    float bias = b[t];
#pragma unroll
    for (int i = 0; i < NPB; i++) acc[i] = bias;
    for (int d = 0; d < 128; ++d) {
        float w = W[d * 128 + t];
#pragma unroll
        for (int i = 0; i < NPB; i++) acc[i] += xs[i][d] * w;
    }
#pragma unroll
    for (int i = 0; i < NPB; i++) {
        int nn = n0 + i;
        if (nn < n) out[(size_t)nn * 128 + t] = acc[i];
    }
}

// ---------------- repack W_stack[ell] (8,128,16) -> Wt (128,128) ----------------

__global__ void repack_kernel(const float* __restrict__ W, float* __restrict__ Wt) {
    int i = blockIdx.x * 256 + threadIdx.x;  // i = head*2048 + d*16 + f
    if (i < 16384) {
        int head = i >> 11;
        int rem = i & 2047;
        int d = rem >> 4;
        int f = rem & 15;
        Wt[d * 128 + head * 16 + f] = W[i];
    }
}

// ---------------- transform: h = xc @ Wt, plus alpha_src/alpha_dst ----------------

__global__ void transform_kernel(const float* __restrict__ xc, const float* __restrict__ Wt,
                                 const float* __restrict__ a, float* __restrict__ h,
                                 float* __restrict__ asrc, float* __restrict__ adst, int n) {
    __shared__ float xs[NPB][128];
    int t = threadIdx.x;  // col t = head*16 + f
    int n0 = blockIdx.x * NPB;
#pragma unroll
    for (int i = 0; i < NPB; i++) {
        int nn = n0 + i;
        xs[i][t] = (nn < n) ? xc[(size_t)nn * 128 + t] : 0.f;
    }
    __syncthreads();
    float acc[NPB];
#pragma unroll
    for (int i = 0; i < NPB; i++) acc[i] = 0.f;
    for (int d = 0; d < 128; ++d) {
        float w = Wt[d * 128 + t];
#pragma unroll
        for (int i = 0; i < NPB; i++) acc[i] += xs[i][d] * w;
    }
    int head = t >> 4, f = t & 15;
    float a_s = a[head * 32 + f];
    float a_d = a[head * 32 + 16 + f];
#pragma unroll
    for (int i = 0; i < NPB; i++) {
        int nn = n0 + i;
        if (nn >= n) break;  // uniform across block
        h[(size_t)nn * 128 + t] = acc[i];
        float ps = acc[i] * a_s;
        float pd = acc[i] * a_d;
#pragma unroll
        for (int off = 8; off; off >>= 1) {
            ps += __shfl_down(ps, off, 16);
            pd += __shfl_down(pd, off, 16);
        }
        if (f == 0) {
            asrc[nn * 8 + head] = ps;
            adst[nn * 8 + head] = pd;
        }
    }
}

// ---------------- aggregate: softmax-weighted neighbor sum ----------------
// mode 0: out = elu(agg)          (layer 0)
// mode 1: out = agg + resid       (layer 1, final)

__global__ void aggregate_kernel(const int* __restrict__ rowptr, const int* __restrict__ col,
                                 const float* __restrict__ val, const float* __restrict__ h,
                                 const float* __restrict__ asrc, const float* __restrict__ adst,
                                 const float* __restrict__ resid, float* __restrict__ out,
                                 int mode, int n) {
    int nd = blockIdx.x;
    if (nd >= n) return;
    int t = threadIdx.x;  // 128 threads; feature t, head = t>>4
    int head = t >> 4;
    float as = asrc[nd * 8 + head];
    int s = rowptr[nd], e = rowptr[nd + 1];
    float acc = 0.f, wsum = 0.f;
    for (int i = s; i < e; ++i) {
        int c = col[i];
        float v = val[i];
        float ad = adst[c * 8 + head];
        float logit = v * (as + ad);
        float lr = logit > 0.f ? logit : 0.2f * logit;
        float w = expf(lr);
        wsum += w;
        acc += w * h[(size_t)c * 128 + t];
    }
    float o = acc / wsum;  // every node has a self-loop -> wsum > 0
    if (mode == 0) {
        o = o > 0.f ? o : expm1f(o);
        out[(size_t)nd * 128 + t] = o;
    } else {
        out[(size_t)nd * 128 + t] = o + resid[(size_t)nd * 128 + t];
    }
}

// ---------------- launch ----------------

extern "C" void kernel_launch(void* const* d_in, const int* in_sizes, int n_in,
                              void* d_out, int out_size, void* d_ws, size_t ws_size,
                              hipStream_t stream) {
    const int N = in_sizes[0] / 128;
    const int E = in_sizes[2];

    const float* x      = (const float*)d_in[0];
    const int*   eidx   = (const int*)d_in[1];   // row = eidx[0:E], col = eidx[E:2E]
    const float* ev     = (const float*)d_in[2];
    const float* encW   = (const float*)d_in[3];
    const float* encb   = (const float*)d_in[4];
    const float* Wstack = (const float*)d_in[5]; // (2,8,128,16)
    const float* astack = (const float*)d_in[6]; // (2,8,32)
    float* out = (float*)d_out;

    const int* row = eidx;
    const int* colv = eidx + E;

    // workspace layout (~88 MB)
    char* p = (char*)d_ws;
    float* xcA  = (float*)p; p += (size_t)N * 128 * 4;
    float* xcB  = (float*)p; p += (size_t)N * 128 * 4;
    float* hbuf = (float*)p; p += (size_t)N * 128 * 4;
    float* asrc = (float*)p; p += (size_t)N * 8 * 4;
    float* adst = (float*)p; p += (size_t)N * 8 * 4;
    float* Wt   = (float*)p; p += 16384 * 4;
    int* rowptr = (int*)p;   p += (size_t)(N + 1) * 4;
    int* cursor = (int*)p;   p += (size_t)N * 4;
    int* deg    = (int*)p;   p += (size_t)N * 4;
    int* csr_col = (int*)p;  p += (size_t)E * 4;
    float* csr_val = (float*)p;

    // --- CSR build ---
    hipMemsetAsync(deg, 0, (size_t)N * 4, stream);
    hist_kernel<<<(E + 255) / 256, 256, 0, stream>>>(row, deg, E);
    scan_kernel<<<1, 1024, 0, stream>>>(deg, rowptr, cursor, N);
    scatter_kernel<<<(E + 255) / 256, 256, 0, stream>>>(row, colv, ev, cursor, csr_col, csr_val, E);

    // --- encoder ---
    encoder_kernel<<<(N + NPB - 1) / NPB, 128, 0, stream>>>(x, encW, encb, xcA, N);

    // --- layer 0 ---
    repack_kernel<<<64, 256, 0, stream>>>(Wstack, Wt);
    transform_kernel<<<(N + NPB - 1) / NPB, 128, 0, stream>>>(xcA, Wt, astack, hbuf, asrc, adst, N);
    aggregate_kernel<<<N, 128, 0, stream>>>(rowptr, csr_col, csr_val, hbuf, asrc, adst,
                                            nullptr, xcB, 0, N);

    // --- layer 1 (final -> d_out, residual with layer-0 output) ---
    repack_kernel<<<64, 256, 0, stream>>>(Wstack + 16384, Wt);
    transform_kernel<<<(N + NPB - 1) / NPB, 128, 0, stream>>>(xcB, Wt, astack + 256, hbuf, asrc, adst, N);
    aggregate_kernel<<<N, 128, 0, stream>>>(rowptr, csr_col, csr_val, hbuf, asrc, adst,
                                            xcB, out, 1, N);
}

// Round 2
// 470.339 us; speedup vs baseline: 1.2694x; 1.2694x over previous
//
#include <hip/hip_runtime.h>
#include <hip/hip_bf16.h>

// GAT: N=50000, E=850000, HID=128, HEADS=8, DH=16, LAYERS=2.
// R2: LDS-staged edge weights in aggregate (compute each (edge,head) weight once),
//     fused encoder+transform0, float4 LDS reads in GEMMs, multi-block scan.

#define TNPB 16     // nodes per block in GEMM kernels
#define CHUNK 64    // edges per LDS chunk in aggregate

// ---------------- CSR build ----------------

__global__ void hist_kernel(const int* __restrict__ row, int* __restrict__ deg, int E) {
    int e = blockIdx.x * 256 + threadIdx.x;
    if (e < E) atomicAdd(&deg[row[e]], 1);
}

__global__ void blocksum_kernel(const int* __restrict__ deg, int* __restrict__ bsum, int n) {
    __shared__ int sd[512];
    int t = threadIdx.x;
    int idx = blockIdx.x * 512 + t;
    sd[t] = (idx < n) ? deg[idx] : 0;
    __syncthreads();
    for (int off = 256; off; off >>= 1) {
        if (t < off) sd[t] += sd[t + off];
        __syncthreads();
    }
    if (t == 0) bsum[blockIdx.x] = sd[0];
}

__global__ void scanbsum_kernel(const int* __restrict__ bsum, int* __restrict__ boff,
                                int nb, int* __restrict__ rowptr, int n) {
    // 128 threads, nb <= 128
    __shared__ int sd[128];
    int t = threadIdx.x;
    int v = (t < nb) ? bsum[t] : 0;
    sd[t] = v;
    __syncthreads();
    for (int off = 1; off < 128; off <<= 1) {
        int add = (t >= off) ? sd[t - off] : 0;
        __syncthreads();
        sd[t] += add;
        __syncthreads();
    }
    if (t < nb) boff[t] = sd[t] - v;
    if (t == nb - 1) rowptr[n] = sd[t];
}

__global__ void scanfinal_kernel(const int* __restrict__ deg, const int* __restrict__ boff,
                                 int* __restrict__ rowptr, int* __restrict__ cursor, int n) {
    __shared__ int sd[512];
    int t = threadIdx.x;
    int idx = blockIdx.x * 512 + t;
    int v = (idx < n) ? deg[idx] : 0;
    sd[t] = v;
    __syncthreads();
    for (int off = 1; off < 512; off <<= 1) {
        int add = (t >= off) ? sd[t - off] : 0;
        __syncthreads();
        sd[t] += add;
        __syncthreads();
    }
    if (idx < n) {
        int excl = sd[t] - v + boff[blockIdx.x];
        rowptr[idx] = excl;
        cursor[idx] = excl;
    }
}

__global__ void scatter_kernel(const int* __restrict__ row, const int* __restrict__ colv,
                               const float* __restrict__ ev, int* __restrict__ cursor,
                               int* __restrict__ csr_col, float* __restrict__ csr_val, int E) {
    int e = blockIdx.x * 256 + threadIdx.x;
    if (e < E) {
        int r = row[e];
        int slot = atomicAdd(&cursor[r], 1);
        csr_col[slot] = colv[e];
        csr_val[slot] = ev[e];
    }
}

// ---------------- repack W_stack (2,8,128,16) -> Wt0, Wt1 (128,128) ----------------

__global__ void repack_kernel(const float* __restrict__ W, float* __restrict__ Wt0,
                              float* __restrict__ Wt1) {
    int i = blockIdx.x * 256 + threadIdx.x;  // 0..32767
    if (i < 32768) {
        int ell = i >> 14;
        int r = i & 16383;
        int head = r >> 11;
        int rem = r & 2047;
        int d = rem >> 4;
        int f = rem & 15;
        float* Wt = ell ? Wt1 : Wt0;
        Wt[d * 128 + head * 16 + f] = W[i];
    }
}

// ---------------- fused encoder + transform (layer 0) ----------------
// xc = x @ encW + b (kept in LDS); h = xc @ Wt; alpha_src/dst via shuffle.

__global__ void enc_transform_kernel(const float* __restrict__ x, const float* __restrict__ encW,
                                     const float* __restrict__ encb, const float* __restrict__ Wt,
                                     const float* __restrict__ a, float* __restrict__ hout,
                                     float* __restrict__ asrc, float* __restrict__ adst, int n) {
    __shared__ float xs[TNPB][128];
    __shared__ float cs[TNPB][128];
    int t = threadIdx.x;
    int n0 = blockIdx.x * TNPB;
#pragma unroll
    for (int i = 0; i < TNPB; i++) {
        int nn = min(n0 + i, n - 1);
        xs[i][t] = x[(size_t)nn * 128 + t];
    }
    __syncthreads();
    float acc[TNPB];
    float bias = encb[t];
#pragma unroll
    for (int i = 0; i < TNPB; i++) acc[i] = bias;
    for (int d4 = 0; d4 < 32; ++d4) {
        float w0 = encW[(d4 * 4 + 0) * 128 + t];
        float w1 = encW[(d4 * 4 + 1) * 128 + t];
        float w2 = encW[(d4 * 4 + 2) * 128 + t];
        float w3 = encW[(d4 * 4 + 3) * 128 + t];
#pragma unroll
        for (int i = 0; i < TNPB; i++) {
            float4 xv = ((const float4*)xs[i])[d4];
            acc[i] += xv.x * w0 + xv.y * w1 + xv.z * w2 + xv.w * w3;
        }
    }
#pragma unroll
    for (int i = 0; i < TNPB; i++) cs[i][t] = acc[i];
    __syncthreads();
#pragma unroll
    for (int i = 0; i < TNPB; i++) acc[i] = 0.f;
    for (int d4 = 0; d4 < 32; ++d4) {
        float w0 = Wt[(d4 * 4 + 0) * 128 + t];
        float w1 = Wt[(d4 * 4 + 1) * 128 + t];
        float w2 = Wt[(d4 * 4 + 2) * 128 + t];
        float w3 = Wt[(d4 * 4 + 3) * 128 + t];
#pragma unroll
        for (int i = 0; i < TNPB; i++) {
            float4 xv = ((const float4*)cs[i])[d4];
            acc[i] += xv.x * w0 + xv.y * w1 + xv.z * w2 + xv.w * w3;
        }
    }
    int headq = t >> 4, f = t & 15;
    float a_s = a[headq * 32 + f];
    float a_d = a[headq * 32 + 16 + f];
#pragma unroll
    for (int i = 0; i < TNPB; i++) {
        int nn = n0 + i;
        if (nn >= n) break;
        hout[nn * 128 + t] = acc[i];
        float ps = acc[i] * a_s;
        float pd = acc[i] * a_d;
#pragma unroll
        for (int off = 8; off; off >>= 1) {
            ps += __shfl_down(ps, off, 16);
            pd += __shfl_down(pd, off, 16);
        }
        if (f == 0) {
            asrc[nn * 8 + headq] = ps;
            adst[nn * 8 + headq] = pd;
        }
    }
}

// ---------------- transform (layer 1) ----------------

__global__ void transform_kernel(const float* __restrict__ xc, const float* __restrict__ Wt,
                                 const float* __restrict__ a, float* __restrict__ hout,
                                 float* __restrict__ asrc, float* __restrict__ adst, int n) {
    __shared__ float xs[TNPB][128];
    int t = threadIdx.x;
    int n0 = blockIdx.x * TNPB;
#pragma unroll
    for (int i = 0; i < TNPB; i++) {
        int nn = min(n0 + i, n - 1);
        xs[i][t] = xc[(size_t)nn * 128 + t];
    }
    __syncthreads();
    float acc[TNPB];
#pragma unroll
    for (int i = 0; i < TNPB; i++) acc[i] = 0.f;
    for (int d4 = 0; d4 < 32; ++d4) {
        float w0 = Wt[(d4 * 4 + 0) * 128 + t];
        float w1 = Wt[(d4 * 4 + 1) * 128 + t];
        float w2 = Wt[(d4 * 4 + 2) * 128 + t];
        float w3 = Wt[(d4 * 4 + 3) * 128 + t];
#pragma unroll
        for (int i = 0; i < TNPB; i++) {
            float4 xv = ((const float4*)xs[i])[d4];
            acc[i] += xv.x * w0 + xv.y * w1 + xv.z * w2 + xv.w * w3;
        }
    }
    int headq = t >> 4, f = t & 15;
    float a_s = a[headq * 32 + f];
    float a_d = a[headq * 32 + 16 + f];
#pragma unroll
    for (int i = 0; i < TNPB; i++) {
        int nn = n0 + i;
        if (nn >= n) break;
        hout[nn * 128 + t] = acc[i];
        float ps = acc[i] * a_s;
        float pd = acc[i] * a_d;
#pragma unroll
        for (int off = 8; off; off >>= 1) {
            ps += __shfl_down(ps, off, 16);
            pd += __shfl_down(pd, off, 16);
        }
        if (f == 0) {
            asrc[nn * 8 + headq] = ps;
            adst[nn * 8 + headq] = pd;
        }
    }
}

// ---------------- aggregate with LDS-staged weights ----------------
// Weight phase: thread t handles head (t&7), edges (t>>3)+16k -> each (edge,head)
// weight computed exactly once per block. Accumulate phase: thread t = feature t.

__global__ void aggregate_kernel(const int* __restrict__ rowptr, const int* __restrict__ col,
                                 const float* __restrict__ val, const float* __restrict__ h,
                                 const float* __restrict__ asrc, const float* __restrict__ adst,
                                 const float* __restrict__ resid, float* __restrict__ out,
                                 int mode, int n) {
    __shared__ float w_lds[CHUNK * 8];
    __shared__ int c_lds[CHUNK];
    __shared__ float v_lds[CHUNK];
    int nd = blockIdx.x;
    if (nd >= n) return;
    int t = threadIdx.x;
    int head = t >> 4;
    int h2 = t & 7;
    int jbase = t >> 3;
    float as_w = asrc[nd * 8 + h2];
    int s = rowptr[nd], e = rowptr[nd + 1];
    float acc = 0.f, wsum = 0.f;
    for (int c0 = s; c0 < e; c0 += CHUNK) {
        int cnt = min(CHUNK, e - c0);
        __syncthreads();  // previous accumulate phase done before LDS overwrite
        if (t < cnt) {
            c_lds[t] = col[c0 + t];
            v_lds[t] = val[c0 + t];
        }
        __syncthreads();
        for (int j = jbase; j < cnt; j += 16) {
            int c = c_lds[j];
            float lg = v_lds[j] * (as_w + adst[c * 8 + h2]);
            float lr = lg > 0.f ? lg : 0.2f * lg;
            w_lds[j * 8 + h2] = __expf(lr);
        }
        __syncthreads();
        for (int j = 0; j < cnt; ++j) {
            int c = c_lds[j];
            float w = w_lds[j * 8 + head];
            wsum += w;
            acc += w * h[c * 128 + t];
        }
    }
    float o = acc / wsum;  // self-loop guarantees wsum > 0
    if (mode == 0) {
        o = o > 0.f ? o : expm1f(o);
        out[nd * 128 + t] = o;
    } else {
        out[nd * 128 + t] = o + resid[nd * 128 + t];
    }
}

// ---------------- launch ----------------

extern "C" void kernel_launch(void* const* d_in, const int* in_sizes, int n_in,
                              void* d_out, int out_size, void* d_ws, size_t ws_size,
                              hipStream_t stream) {
    const int N = in_sizes[0] / 128;
    const int E = in_sizes[2];

    const float* x      = (const float*)d_in[0];
    const int*   eidx   = (const int*)d_in[1];
    const float* ev     = (const float*)d_in[2];
    const float* encW   = (const float*)d_in[3];
    const float* encb   = (const float*)d_in[4];
    const float* Wstack = (const float*)d_in[5];
    const float* astack = (const float*)d_in[6];
    float* out = (float*)d_out;

    const int* row = eidx;
    const int* colv = eidx + E;

    char* p = (char*)d_ws;
    float* xcB  = (float*)p; p += (size_t)N * 128 * 4;
    float* hbuf = (float*)p; p += (size_t)N * 128 * 4;
    float* asrc = (float*)p; p += (size_t)N * 8 * 4;
    float* adst = (float*)p; p += (size_t)N * 8 * 4;
    float* Wt0  = (float*)p; p += 16384 * 4;
    float* Wt1  = (float*)p; p += 16384 * 4;
    int* rowptr = (int*)p;   p += (size_t)(N + 1) * 4;
    int* cursor = (int*)p;   p += (size_t)N * 4;
    int* deg    = (int*)p;   p += (size_t)N * 4;
    int* bsum   = (int*)p;   p += 128 * 4;
    int* boff   = (int*)p;   p += 128 * 4;
    int* csr_col = (int*)p;  p += (size_t)E * 4;
    float* csr_val = (float*)p;

    const int NB = (N + 511) / 512;  // 98 <= 128

    // --- CSR build ---
    hipMemsetAsync(deg, 0, (size_t)N * 4, stream);
    hist_kernel<<<(E + 255) / 256, 256, 0, stream>>>(row, deg, E);
    blocksum_kernel<<<NB, 512, 0, stream>>>(deg, bsum, N);
    scanbsum_kernel<<<1, 128, 0, stream>>>(bsum, boff, NB, rowptr, N);
    scanfinal_kernel<<<NB, 512, 0, stream>>>(deg, boff, rowptr, cursor, N);
    scatter_kernel<<<(E + 255) / 256, 256, 0, stream>>>(row, colv, ev, cursor, csr_col, csr_val, E);

    // --- weights repack (both layers) ---
    repack_kernel<<<128, 256, 0, stream>>>(Wstack, Wt0, Wt1);

    // --- layer 0 (fused encoder + transform) ---
    enc_transform_kernel<<<(N + TNPB - 1) / TNPB, 128, 0, stream>>>(
        x, encW, encb, Wt0, astack, hbuf, asrc, adst, N);
    aggregate_kernel<<<N, 128, 0, stream>>>(rowptr, csr_col, csr_val, hbuf, asrc, adst,
                                            nullptr, xcB, 0, N);

    // --- layer 1 ---
    transform_kernel<<<(N + TNPB - 1) / TNPB, 128, 0, stream>>>(
        xcB, Wt1, astack + 256, hbuf, asrc, adst, N);
    aggregate_kernel<<<N, 128, 0, stream>>>(rowptr, csr_col, csr_val, hbuf, asrc, adst,
                                            xcB, out, 1, N);
}

// Round 3
// 402.462 us; speedup vs baseline: 1.4835x; 1.1687x over previous
//
#include <hip/hip_runtime.h>
#include <hip/hip_bf16.h>

// GAT: N=50000, E=850000, HID=128, HEADS=8, DH=16, LAYERS=2.
// R3: GEMMs moved to MFMA (bf16 hi/lo split for fp32-equivalent precision),
//     W pre-packed into B-fragment layout, alpha fused in GEMM epilogue.
//     Aggregate + CSR unchanged from R2.

#define CHUNK 64    // edges per LDS chunk in aggregate

typedef __attribute__((ext_vector_type(8))) short short8;   // 8 bf16 = 4 VGPRs
typedef __attribute__((ext_vector_type(4))) float floatx4;

__device__ __forceinline__ unsigned f2u(float f) { return __float_as_uint(f); }
__device__ __forceinline__ float u2f(unsigned u) { return __uint_as_float(u); }

// ---------------- CSR build ----------------

__global__ void hist_kernel(const int* __restrict__ row, int* __restrict__ deg, int E) {
    int e = blockIdx.x * 256 + threadIdx.x;
    if (e < E) atomicAdd(&deg[row[e]], 1);
}

__global__ void blocksum_kernel(const int* __restrict__ deg, int* __restrict__ bsum, int n) {
    __shared__ int sd[512];
    int t = threadIdx.x;
    int idx = blockIdx.x * 512 + t;
    sd[t] = (idx < n) ? deg[idx] : 0;
    __syncthreads();
    for (int off = 256; off; off >>= 1) {
        if (t < off) sd[t] += sd[t + off];
        __syncthreads();
    }
    if (t == 0) bsum[blockIdx.x] = sd[0];
}

__global__ void scanbsum_kernel(const int* __restrict__ bsum, int* __restrict__ boff,
                                int nb, int* __restrict__ rowptr, int n) {
    __shared__ int sd[128];
    int t = threadIdx.x;
    int v = (t < nb) ? bsum[t] : 0;
    sd[t] = v;
    __syncthreads();
    for (int off = 1; off < 128; off <<= 1) {
        int add = (t >= off) ? sd[t - off] : 0;
        __syncthreads();
        sd[t] += add;
        __syncthreads();
    }
    if (t < nb) boff[t] = sd[t] - v;
    if (t == nb - 1) rowptr[n] = sd[t];
}

__global__ void scanfinal_kernel(const int* __restrict__ deg, const int* __restrict__ boff,
                                 int* __restrict__ rowptr, int* __restrict__ cursor, int n) {
    __shared__ int sd[512];
    int t = threadIdx.x;
    int idx = blockIdx.x * 512 + t;
    int v = (idx < n) ? deg[idx] : 0;
    sd[t] = v;
    __syncthreads();
    for (int off = 1; off < 512; off <<= 1) {
        int add = (t >= off) ? sd[t - off] : 0;
        __syncthreads();
        sd[t] += add;
        __syncthreads();
    }
    if (idx < n) {
        int excl = sd[t] - v + boff[blockIdx.x];
        rowptr[idx] = excl;
        cursor[idx] = excl;
    }
}

__global__ void scatter_kernel(const int* __restrict__ row, const int* __restrict__ colv,
                               const float* __restrict__ ev, int* __restrict__ cursor,
                               int* __restrict__ csr_col, float* __restrict__ csr_val, int E) {
    int e = blockIdx.x * 256 + threadIdx.x;
    if (e < E) {
        int r = row[e];
        int slot = atomicAdd(&cursor[r], 1);
        csr_col[slot] = colv[e];
        csr_val[slot] = ev[e];
    }
}

// ---------------- W pack: fp32 -> split-bf16 B-fragment layout ----------------
// Fragment f at flat index (mat*2048 + (ct*4+kt)*64 + lane) holds 8 bf16:
//   B[k = kt*32 + (lane>>4)*8 + j][n = ct*16 + (lane&15)],  j = 0..7
// mat 0: encW (128x128 row-major [k][n])
// mat 1,2: W_stack[ell] (8,128,16) -> head-concat column layout n = head*16+f.

__global__ void pack_kernel(const float* __restrict__ encW, const float* __restrict__ Wstack,
                            short8* __restrict__ Wh, short8* __restrict__ Wl) {
    int idx = blockIdx.x * 256 + threadIdx.x;
    if (idx >= 3 * 2048) return;
    int mat = idx >> 11;
    int r = idx & 2047;
    int lane = r & 63;
    int tile = r >> 6;            // ct*4 + kt
    int ct = tile >> 2, kt = tile & 3;
    int ncol = ct * 16 + (lane & 15);
    int k0 = kt * 32 + ((lane >> 4) * 8);
    short8 hv, lv;
#pragma unroll
    for (int j = 0; j < 8; ++j) {
        int k = k0 + j;
        float w = (mat == 0)
            ? encW[k * 128 + ncol]
            : Wstack[(mat - 1) * 16384 + (ncol >> 4) * 2048 + k * 16 + (ncol & 15)];
        unsigned u = f2u(w);
        hv[j] = (short)(u >> 16);
        float hf = u2f(u & 0xFFFF0000u);
        float l = w - hf;
        lv[j] = (short)(f2u(l) >> 16);
    }
    Wh[idx] = hv;
    Wl[idx] = lv;
}

// ---------------- MFMA GEMM: C = A @ B (+bias) (+alpha epilogue) ----------------
// A: n x 128 fp32.  B: packed split-bf16 (2048 frags).  C: n x 128 fp32.
// 256 threads = 4 waves; wave handles 16 nodes x 128 cols.
// flags: bit0 = add bias, bit1 = compute alpha_src/adst.

__global__ __launch_bounds__(256) void
gemm_mfma(const float* __restrict__ A, const short8* __restrict__ Bh,
          const short8* __restrict__ Bl, const float* __restrict__ bias,
          const float* __restrict__ avec, float* __restrict__ C,
          float* __restrict__ asrc, float* __restrict__ adst, int n, int flags) {
    int wave = threadIdx.x >> 6;
    int lane = threadIdx.x & 63;
    int q = lane >> 4;          // 0..3
    int col = lane & 15;        // C column within tile; also A row within tile
    int n0w = blockIdx.x * 64 + wave * 16;

    // --- load + split A fragments (16 rows x K=128) ---
    int arow = min(n0w + col, n - 1);
    const float* Arow = A + (size_t)arow * 128;
    int kb = q * 8;
    short8 Ah[4], Al[4];
#pragma unroll
    for (int kt = 0; kt < 4; ++kt) {
        float4 f0 = *(const float4*)(Arow + kt * 32 + kb);
        float4 f1 = *(const float4*)(Arow + kt * 32 + kb + 4);
        float fv[8] = {f0.x, f0.y, f0.z, f0.w, f1.x, f1.y, f1.z, f1.w};
#pragma unroll
        for (int j = 0; j < 8; ++j) {
            unsigned u = f2u(fv[j]);
            Ah[kt][j] = (short)(u >> 16);
            float hf = u2f(u & 0xFFFF0000u);
            float l = fv[j] - hf;
            Al[kt][j] = (short)(f2u(l) >> 16);
        }
    }

    int nbase = n0w + q * 4;
#pragma unroll
    for (int ct = 0; ct < 8; ++ct) {
        short8 bh[4], bl[4];
#pragma unroll
        for (int kt = 0; kt < 4; ++kt) {
            bh[kt] = Bh[(ct * 4 + kt) * 64 + lane];
            bl[kt] = Bl[(ct * 4 + kt) * 64 + lane];
        }
        float bv = (flags & 1) ? bias[ct * 16 + col] : 0.f;
        floatx4 acc = {bv, bv, bv, bv};
#pragma unroll
        for (int kt = 0; kt < 4; ++kt) {
            acc = __builtin_amdgcn_mfma_f32_16x16x32_bf16(Ah[kt], bh[kt], acc, 0, 0, 0);
            acc = __builtin_amdgcn_mfma_f32_16x16x32_bf16(Al[kt], bh[kt], acc, 0, 0, 0);
            acc = __builtin_amdgcn_mfma_f32_16x16x32_bf16(Ah[kt], bl[kt], acc, 0, 0, 0);
        }
        // store C
#pragma unroll
        for (int reg = 0; reg < 4; ++reg) {
            int node = nbase + reg;
            if (node < n) C[(size_t)node * 128 + ct * 16 + col] = acc[reg];
        }
        if (flags & 2) {
            // head == ct: alpha[node][ct] = sum_col acc * a[ct*32 (+16) + col]
            float a_s = avec[ct * 32 + col];
            float a_d = avec[ct * 32 + 16 + col];
#pragma unroll
            for (int reg = 0; reg < 4; ++reg) {
                float ps = acc[reg] * a_s;
                float pd = acc[reg] * a_d;
#pragma unroll
                for (int off = 8; off; off >>= 1) {
                    ps += __shfl_down(ps, off, 16);
                    pd += __shfl_down(pd, off, 16);
                }
                int node = nbase + reg;
                if (col == 0 && node < n) {
                    asrc[node * 8 + ct] = ps;
                    adst[node * 8 + ct] = pd;
                }
            }
        }
    }
}

// ---------------- aggregate with LDS-staged weights ----------------

__global__ void aggregate_kernel(const int* __restrict__ rowptr, const int* __restrict__ col,
                                 const float* __restrict__ val, const float* __restrict__ h,
                                 const float* __restrict__ asrc, const float* __restrict__ adst,
                                 const float* __restrict__ resid, float* __restrict__ out,
                                 int mode, int n) {
    __shared__ float w_lds[CHUNK * 8];
    __shared__ int c_lds[CHUNK];
    __shared__ float v_lds[CHUNK];
    int nd = blockIdx.x;
    if (nd >= n) return;
    int t = threadIdx.x;
    int head = t >> 4;
    int h2 = t & 7;
    int jbase = t >> 3;
    float as_w = asrc[nd * 8 + h2];
    int s = rowptr[nd], e = rowptr[nd + 1];
    float acc = 0.f, wsum = 0.f;
    for (int c0 = s; c0 < e; c0 += CHUNK) {
        int cnt = min(CHUNK, e - c0);
        __syncthreads();
        if (t < cnt) {
            c_lds[t] = col[c0 + t];
            v_lds[t] = val[c0 + t];
        }
        __syncthreads();
        for (int j = jbase; j < cnt; j += 16) {
            int c = c_lds[j];
            float lg = v_lds[j] * (as_w + adst[c * 8 + h2]);
            float lr = lg > 0.f ? lg : 0.2f * lg;
            w_lds[j * 8 + h2] = __expf(lr);
        }
        __syncthreads();
        for (int j = 0; j < cnt; ++j) {
            int c = c_lds[j];
            float w = w_lds[j * 8 + head];
            wsum += w;
            acc += w * h[c * 128 + t];
        }
    }
    float o = acc / wsum;
    if (mode == 0) {
        o = o > 0.f ? o : expm1f(o);
        out[nd * 128 + t] = o;
    } else {
        out[nd * 128 + t] = o + resid[nd * 128 + t];
    }
}

// ---------------- launch ----------------

extern "C" void kernel_launch(void* const* d_in, const int* in_sizes, int n_in,
                              void* d_out, int out_size, void* d_ws, size_t ws_size,
                              hipStream_t stream) {
    const int N = in_sizes[0] / 128;
    const int E = in_sizes[2];

    const float* x      = (const float*)d_in[0];
    const int*   eidx   = (const int*)d_in[1];
    const float* ev     = (const float*)d_in[2];
    const float* encW   = (const float*)d_in[3];
    const float* encb   = (const float*)d_in[4];
    const float* Wstack = (const float*)d_in[5];
    const float* astack = (const float*)d_in[6];
    float* out = (float*)d_out;

    const int* row = eidx;
    const int* colv = eidx + E;

    char* p = (char*)d_ws;
    float* xc   = (float*)p; p += (size_t)N * 128 * 4;
    float* xcB  = (float*)p; p += (size_t)N * 128 * 4;
    float* hbuf = (float*)p; p += (size_t)N * 128 * 4;
    float* asrc = (float*)p; p += (size_t)N * 8 * 4;
    float* adst = (float*)p; p += (size_t)N * 8 * 4;
    short8* Wh  = (short8*)p; p += 3 * 2048 * 16;
    short8* Wl  = (short8*)p; p += 3 * 2048 * 16;
    int* rowptr = (int*)p;   p += (size_t)(N + 1) * 4;
    int* cursor = (int*)p;   p += (size_t)N * 4;
    int* deg    = (int*)p;   p += (size_t)N * 4;
    int* bsum   = (int*)p;   p += 128 * 4;
    int* boff   = (int*)p;   p += 128 * 4;
    int* csr_col = (int*)p;  p += (size_t)E * 4;
    float* csr_val = (float*)p;

    const int NB = (N + 511) / 512;
    const int GB = (N + 63) / 64;   // gemm blocks

    // --- CSR build ---
    hipMemsetAsync(deg, 0, (size_t)N * 4, stream);
    hist_kernel<<<(E + 255) / 256, 256, 0, stream>>>(row, deg, E);
    blocksum_kernel<<<NB, 512, 0, stream>>>(deg, bsum, N);
    scanbsum_kernel<<<1, 128, 0, stream>>>(bsum, boff, NB, rowptr, N);
    scanfinal_kernel<<<NB, 512, 0, stream>>>(deg, boff, rowptr, cursor, N);
    scatter_kernel<<<(E + 255) / 256, 256, 0, stream>>>(row, colv, ev, cursor, csr_col, csr_val, E);

    // --- pack weights (all three matrices, hi/lo split) ---
    pack_kernel<<<24, 256, 0, stream>>>(encW, Wstack, Wh, Wl);

    // --- encoder: xc = x @ encW + b ---
    gemm_mfma<<<GB, 256, 0, stream>>>(x, Wh, Wl, encb, nullptr, xc,
                                      nullptr, nullptr, N, 1);

    // --- layer 0: h0 = xc @ Wt0, alpha0 ---
    gemm_mfma<<<GB, 256, 0, stream>>>(xc, Wh + 2048, Wl + 2048, nullptr, astack, hbuf,
                                      asrc, adst, N, 2);
    aggregate_kernel<<<N, 128, 0, stream>>>(rowptr, csr_col, csr_val, hbuf, asrc, adst,
                                            nullptr, xcB, 0, N);

    // --- layer 1: h1 = xcB @ Wt1, alpha1 ---
    gemm_mfma<<<GB, 256, 0, stream>>>(xcB, Wh + 4096, Wl + 4096, nullptr, astack + 256, hbuf,
                                      asrc, adst, N, 2);
    aggregate_kernel<<<N, 128, 0, stream>>>(rowptr, csr_col, csr_val, hbuf, asrc, adst,
                                            xcB, out, 1, N);
}

// Round 4
// 352.038 us; speedup vs baseline: 1.6960x; 1.1432x over previous
//
#include <hip/hip_runtime.h>
#include <hip/hip_bf16.h>

// GAT: N=50000, E=850000, HID=128, HEADS=8, DH=16, LAYERS=2.
// R4: h stored as bf16 (halves gather traffic), aggregate restructured to
//     4-edge-parallel groups with ushort4 loads + LDS cross-group reduction.

#define CHUNK 64    // edges per LDS chunk in aggregate

typedef __attribute__((ext_vector_type(8))) short short8;   // 8 bf16 = 4 VGPRs
typedef __attribute__((ext_vector_type(4))) float floatx4;

__device__ __forceinline__ unsigned f2u(float f) { return __float_as_uint(f); }
__device__ __forceinline__ float u2f(unsigned u) { return __uint_as_float(u); }
__device__ __forceinline__ unsigned short f2bf_rne(float x) {
    unsigned u = f2u(x);
    unsigned r = (u + 0x7FFF + ((u >> 16) & 1)) >> 16;
    return (unsigned short)r;
}
__device__ __forceinline__ float bf2f(unsigned short b) { return u2f(((unsigned)b) << 16); }

// ---------------- CSR build ----------------

__global__ void hist_kernel(const int* __restrict__ row, int* __restrict__ deg, int E) {
    int e = blockIdx.x * 256 + threadIdx.x;
    if (e < E) atomicAdd(&deg[row[e]], 1);
}

__global__ void blocksum_kernel(const int* __restrict__ deg, int* __restrict__ bsum, int n) {
    __shared__ int sd[512];
    int t = threadIdx.x;
    int idx = blockIdx.x * 512 + t;
    sd[t] = (idx < n) ? deg[idx] : 0;
    __syncthreads();
    for (int off = 256; off; off >>= 1) {
        if (t < off) sd[t] += sd[t + off];
        __syncthreads();
    }
    if (t == 0) bsum[blockIdx.x] = sd[0];
}

__global__ void scanbsum_kernel(const int* __restrict__ bsum, int* __restrict__ boff,
                                int nb, int* __restrict__ rowptr, int n) {
    __shared__ int sd[128];
    int t = threadIdx.x;
    int v = (t < nb) ? bsum[t] : 0;
    sd[t] = v;
    __syncthreads();
    for (int off = 1; off < 128; off <<= 1) {
        int add = (t >= off) ? sd[t - off] : 0;
        __syncthreads();
        sd[t] += add;
        __syncthreads();
    }
    if (t < nb) boff[t] = sd[t] - v;
    if (t == nb - 1) rowptr[n] = sd[t];
}

__global__ void scanfinal_kernel(const int* __restrict__ deg, const int* __restrict__ boff,
                                 int* __restrict__ rowptr, int* __restrict__ cursor, int n) {
    __shared__ int sd[512];
    int t = threadIdx.x;
    int idx = blockIdx.x * 512 + t;
    int v = (idx < n) ? deg[idx] : 0;
    sd[t] = v;
    __syncthreads();
    for (int off = 1; off < 512; off <<= 1) {
        int add = (t >= off) ? sd[t - off] : 0;
        __syncthreads();
        sd[t] += add;
        __syncthreads();
    }
    if (idx < n) {
        int excl = sd[t] - v + boff[blockIdx.x];
        rowptr[idx] = excl;
        cursor[idx] = excl;
    }
}

__global__ void scatter_kernel(const int* __restrict__ row, const int* __restrict__ colv,
                               const float* __restrict__ ev, int* __restrict__ cursor,
                               int* __restrict__ csr_col, float* __restrict__ csr_val, int E) {
    int e = blockIdx.x * 256 + threadIdx.x;
    if (e < E) {
        int r = row[e];
        int slot = atomicAdd(&cursor[r], 1);
        csr_col[slot] = colv[e];
        csr_val[slot] = ev[e];
    }
}

// ---------------- W pack: fp32 -> split-bf16 B-fragment layout ----------------

__global__ void pack_kernel(const float* __restrict__ encW, const float* __restrict__ Wstack,
                            short8* __restrict__ Wh, short8* __restrict__ Wl) {
    int idx = blockIdx.x * 256 + threadIdx.x;
    if (idx >= 3 * 2048) return;
    int mat = idx >> 11;
    int r = idx & 2047;
    int lane = r & 63;
    int tile = r >> 6;            // ct*4 + kt
    int ct = tile >> 2, kt = tile & 3;
    int ncol = ct * 16 + (lane & 15);
    int k0 = kt * 32 + ((lane >> 4) * 8);
    short8 hv, lv;
#pragma unroll
    for (int j = 0; j < 8; ++j) {
        int k = k0 + j;
        float w = (mat == 0)
            ? encW[k * 128 + ncol]
            : Wstack[(mat - 1) * 16384 + (ncol >> 4) * 2048 + k * 16 + (ncol & 15)];
        unsigned u = f2u(w);
        hv[j] = (short)(u >> 16);
        float hf = u2f(u & 0xFFFF0000u);
        float l = w - hf;
        lv[j] = (short)(f2u(l) >> 16);
    }
    Wh[idx] = hv;
    Wl[idx] = lv;
}

// ---------------- MFMA GEMM ----------------
// flags: bit0 = add bias, bit1 = alpha epilogue, bit2 = store C as bf16.

__global__ __launch_bounds__(256) void
gemm_mfma(const float* __restrict__ A, const short8* __restrict__ Bh,
          const short8* __restrict__ Bl, const float* __restrict__ bias,
          const float* __restrict__ avec, float* __restrict__ Cf,
          unsigned short* __restrict__ Cbf,
          float* __restrict__ asrc, float* __restrict__ adst, int n, int flags) {
    int wave = threadIdx.x >> 6;
    int lane = threadIdx.x & 63;
    int q = lane >> 4;
    int col = lane & 15;
    int n0w = blockIdx.x * 64 + wave * 16;

    int arow = min(n0w + col, n - 1);
    const float* Arow = A + (size_t)arow * 128;
    int kb = q * 8;
    short8 Ah[4], Al[4];
#pragma unroll
    for (int kt = 0; kt < 4; ++kt) {
        float4 f0 = *(const float4*)(Arow + kt * 32 + kb);
        float4 f1 = *(const float4*)(Arow + kt * 32 + kb + 4);
        float fv[8] = {f0.x, f0.y, f0.z, f0.w, f1.x, f1.y, f1.z, f1.w};
#pragma unroll
        for (int j = 0; j < 8; ++j) {
            unsigned u = f2u(fv[j]);
            Ah[kt][j] = (short)(u >> 16);
            float hf = u2f(u & 0xFFFF0000u);
            float l = fv[j] - hf;
            Al[kt][j] = (short)(f2u(l) >> 16);
        }
    }

    int nbase = n0w + q * 4;
#pragma unroll
    for (int ct = 0; ct < 8; ++ct) {
        short8 bh[4], bl[4];
#pragma unroll
        for (int kt = 0; kt < 4; ++kt) {
            bh[kt] = Bh[(ct * 4 + kt) * 64 + lane];
            bl[kt] = Bl[(ct * 4 + kt) * 64 + lane];
        }
        float bv = (flags & 1) ? bias[ct * 16 + col] : 0.f;
        floatx4 acc = {bv, bv, bv, bv};
#pragma unroll
        for (int kt = 0; kt < 4; ++kt) {
            acc = __builtin_amdgcn_mfma_f32_16x16x32_bf16(Ah[kt], bh[kt], acc, 0, 0, 0);
            acc = __builtin_amdgcn_mfma_f32_16x16x32_bf16(Al[kt], bh[kt], acc, 0, 0, 0);
            acc = __builtin_amdgcn_mfma_f32_16x16x32_bf16(Ah[kt], bl[kt], acc, 0, 0, 0);
        }
#pragma unroll
        for (int reg = 0; reg < 4; ++reg) {
            int node = nbase + reg;
            if (node < n) {
                if (flags & 4) Cbf[(size_t)node * 128 + ct * 16 + col] = f2bf_rne(acc[reg]);
                else           Cf[(size_t)node * 128 + ct * 16 + col] = acc[reg];
            }
        }
        if (flags & 2) {
            float a_s = avec[ct * 32 + col];
            float a_d = avec[ct * 32 + 16 + col];
#pragma unroll
            for (int reg = 0; reg < 4; ++reg) {
                float ps = acc[reg] * a_s;
                float pd = acc[reg] * a_d;
#pragma unroll
                for (int off = 8; off; off >>= 1) {
                    ps += __shfl_down(ps, off, 16);
                    pd += __shfl_down(pd, off, 16);
                }
                int node = nbase + reg;
                if (col == 0 && node < n) {
                    asrc[node * 8 + ct] = ps;
                    adst[node * 8 + ct] = pd;
                }
            }
        }
    }
}

// ---------------- aggregate: 4-edge-parallel groups, bf16 h gather ----------------
// Block = 128 threads. Weight phase: thread t -> head t&7, edges t>>3 (+16 stride).
// Accumulate: group g = t>>5 (4 groups), lane l = t&31; group g takes edges
// j = g, g+4, ...; lane l holds features 4l..4l+3 (one head: l>>2 within w row).
// Final: LDS reduction across groups (acc x4 + wsum).

__global__ void aggregate_kernel(const int* __restrict__ rowptr, const int* __restrict__ col,
                                 const float* __restrict__ val,
                                 const unsigned short* __restrict__ hbf,
                                 const float* __restrict__ asrc, const float* __restrict__ adst,
                                 const float* __restrict__ resid, float* __restrict__ out,
                                 int mode, int n) {
    __shared__ float w_lds[CHUNK * 8];
    __shared__ int c_lds[CHUNK];
    __shared__ float v_lds[CHUNK];
    __shared__ float red[4 * 128];
    __shared__ float redw[4 * 128];
    int nd = blockIdx.x;
    if (nd >= n) return;
    int t = threadIdx.x;
    int h2 = t & 7;
    int jbase = t >> 3;
    int g = t >> 5;          // edge group 0..3
    int l = t & 31;          // lane in group; features 4l..4l+3
    int hsub = l >> 2;       // head of this lane's features
    float as_w = asrc[nd * 8 + h2];
    int s = rowptr[nd], e = rowptr[nd + 1];
    float acc0 = 0.f, acc1 = 0.f, acc2 = 0.f, acc3 = 0.f, wsum = 0.f;
    for (int c0 = s; c0 < e; c0 += CHUNK) {
        int cnt = min(CHUNK, e - c0);
        __syncthreads();
        if (t < cnt) {
            c_lds[t] = col[c0 + t];
            v_lds[t] = val[c0 + t];
        }
        __syncthreads();
        for (int j = jbase; j < cnt; j += 16) {
            int c = c_lds[j];
            float lg = v_lds[j] * (as_w + adst[c * 8 + h2]);
            float lr = lg > 0.f ? lg : 0.2f * lg;
            w_lds[j * 8 + h2] = __expf(lr);
        }
        __syncthreads();
        for (int j = g; j < cnt; j += 4) {
            int c = c_lds[j];
            float w = w_lds[j * 8 + hsub];
            ushort4 hv = *(const ushort4*)(hbf + (size_t)c * 128 + l * 4);
            acc0 += w * bf2f(hv.x);
            acc1 += w * bf2f(hv.y);
            acc2 += w * bf2f(hv.z);
            acc3 += w * bf2f(hv.w);
            wsum += w;
        }
    }
    __syncthreads();
    red[g * 128 + l * 4 + 0] = acc0;
    red[g * 128 + l * 4 + 1] = acc1;
    red[g * 128 + l * 4 + 2] = acc2;
    red[g * 128 + l * 4 + 3] = acc3;
    redw[g * 128 + l * 4 + 0] = wsum;
    redw[g * 128 + l * 4 + 1] = wsum;
    redw[g * 128 + l * 4 + 2] = wsum;
    redw[g * 128 + l * 4 + 3] = wsum;
    __syncthreads();
    float a = red[t] + red[128 + t] + red[256 + t] + red[384 + t];
    float ws = redw[t] + redw[128 + t] + redw[256 + t] + redw[384 + t];
    float o = a / ws;   // self-loop guarantees ws > 0
    if (mode == 0) {
        o = o > 0.f ? o : expm1f(o);
        out[(size_t)nd * 128 + t] = o;
    } else {
        out[(size_t)nd * 128 + t] = o + resid[(size_t)nd * 128 + t];
    }
}

// ---------------- launch ----------------

extern "C" void kernel_launch(void* const* d_in, const int* in_sizes, int n_in,
                              void* d_out, int out_size, void* d_ws, size_t ws_size,
                              hipStream_t stream) {
    const int N = in_sizes[0] / 128;
    const int E = in_sizes[2];

    const float* x      = (const float*)d_in[0];
    const int*   eidx   = (const int*)d_in[1];
    const float* ev     = (const float*)d_in[2];
    const float* encW   = (const float*)d_in[3];
    const float* encb   = (const float*)d_in[4];
    const float* Wstack = (const float*)d_in[5];
    const float* astack = (const float*)d_in[6];
    float* out = (float*)d_out;

    const int* row = eidx;
    const int* colv = eidx + E;

    char* p = (char*)d_ws;
    float* xc   = (float*)p; p += (size_t)N * 128 * 4;
    float* xcB  = (float*)p; p += (size_t)N * 128 * 4;
    unsigned short* hbf = (unsigned short*)p; p += (size_t)N * 128 * 2;
    float* asrc = (float*)p; p += (size_t)N * 8 * 4;
    float* adst = (float*)p; p += (size_t)N * 8 * 4;
    short8* Wh  = (short8*)p; p += 3 * 2048 * 16;
    short8* Wl  = (short8*)p; p += 3 * 2048 * 16;
    int* rowptr = (int*)p;   p += (size_t)(N + 1) * 4;
    int* cursor = (int*)p;   p += (size_t)N * 4;
    int* deg    = (int*)p;   p += (size_t)N * 4;
    int* bsum   = (int*)p;   p += 128 * 4;
    int* boff   = (int*)p;   p += 128 * 4;
    int* csr_col = (int*)p;  p += (size_t)E * 4;
    float* csr_val = (float*)p;

    const int NB = (N + 511) / 512;
    const int GB = (N + 63) / 64;

    // --- CSR build ---
    hipMemsetAsync(deg, 0, (size_t)N * 4, stream);
    hist_kernel<<<(E + 255) / 256, 256, 0, stream>>>(row, deg, E);
    blocksum_kernel<<<NB, 512, 0, stream>>>(deg, bsum, N);
    scanbsum_kernel<<<1, 128, 0, stream>>>(bsum, boff, NB, rowptr, N);
    scanfinal_kernel<<<NB, 512, 0, stream>>>(deg, boff, rowptr, cursor, N);
    scatter_kernel<<<(E + 255) / 256, 256, 0, stream>>>(row, colv, ev, cursor, csr_col, csr_val, E);

    // --- pack weights ---
    pack_kernel<<<24, 256, 0, stream>>>(encW, Wstack, Wh, Wl);

    // --- encoder: xc = x @ encW + b (fp32 out) ---
    gemm_mfma<<<GB, 256, 0, stream>>>(x, Wh, Wl, encb, nullptr, xc, nullptr,
                                      nullptr, nullptr, N, 1);

    // --- layer 0: h0 (bf16) + alpha0 ---
    gemm_mfma<<<GB, 256, 0, stream>>>(xc, Wh + 2048, Wl + 2048, nullptr, astack,
                                      nullptr, hbf, asrc, adst, N, 2 | 4);
    aggregate_kernel<<<N, 128, 0, stream>>>(rowptr, csr_col, csr_val, hbf, asrc, adst,
                                            nullptr, xcB, 0, N);

    // --- layer 1: h1 (bf16) + alpha1 ---
    gemm_mfma<<<GB, 256, 0, stream>>>(xcB, Wh + 4096, Wl + 4096, nullptr, astack + 256,
                                      nullptr, hbf, asrc, adst, N, 2 | 4);
    aggregate_kernel<<<N, 128, 0, stream>>>(rowptr, csr_col, csr_val, hbf, asrc, adst,
                                            xcB, out, 1, N);
}